// Round 7
// baseline (55.693 us; speedup 1.0000x reference)
//
#include <hip/hip_runtime.h>
#include <cstddef>

#define T_DIM 30000
#define M_DIM 23
#define PADC  64            // leading pad elements per Ycp column
#define CSTR  30208         // Ycp column stride in elements (16B-aligned, covers 64+30000+halo)
#define TILE  64            // output timesteps per conv block
#define WSTR  132           // wkp per-g stride in floats (bank-decorrelated, 16B-aligned)
#define XP4   377           // reduce LDS pitch in float4

__device__ __forceinline__ unsigned short f2bf(float f) {
    unsigned int u = __float_as_uint(f);
    return (unsigned short)((u + 0x7fffu + ((u >> 16) & 1u)) >> 16);
}
__device__ __forceinline__ float bflo(unsigned int u) { return __uint_as_float(u << 16); }
__device__ __forceinline__ float bfhi(unsigned int u) { return __uint_as_float(u & 0xffff0000u); }

// ---- Kernel B: X (T,1500) fp32 -> Ycp (92 cols x CSTR) bf16, column-major.
// Round-5 LDS-transpose reduce + transposed column write-out.
__global__ __launch_bounds__(256) void reduce_t(const float* __restrict__ X,
                                                unsigned short* __restrict__ Ycp) {
    __shared__ __align__(16) float4 Xs[8 * XP4];           // 48256 B
    __shared__ __align__(16) unsigned short Ytr[92 * 8];   // 1472 B

    const int tid = threadIdx.x;
    const int tb  = blockIdx.x * 8;        // 3750 blocks x 8 rows = 30000 exactly

    const float4* Xg = reinterpret_cast<const float4*>(X) + (size_t)tb * 375;
    #pragma unroll
    for (int it = 0; it < 12; ++it) {
        int i = tid + 256 * it;
        if (i < 3000) {
            int r = i / 375;
            int pos = i - r * 375;
            Xs[r * XP4 + pos] = Xg[i];
        }
    }
    __syncthreads();

    if (tid < 184) {
        int r = tid / 23;
        int q = tid - 23 * r;
        const float4* row = &Xs[r * XP4];
        float4 s = make_float4(0.f, 0.f, 0.f, 0.f);
        #pragma unroll
        for (int k = 0; k < 16; ++k) {
            float4 v = row[q + 23 * k];
            s.x += v.x; s.y += v.y; s.z += v.z; s.w += v.w;
        }
        if (q < 7) {
            float4 v = row[q + 23 * 16];
            s.x += v.x; s.y += v.y; s.z += v.z; s.w += v.w;
        }
        // transpose into Ytr[col][r]
        Ytr[(4 * q + 0) * 8 + r] = f2bf(s.x);
        Ytr[(4 * q + 1) * 8 + r] = f2bf(s.y);
        Ytr[(4 * q + 2) * 8 + r] = f2bf(s.z);
        Ytr[(4 * q + 3) * 8 + r] = f2bf(s.w);
    }
    __syncthreads();

    if (tid < 92) {
        uint4 v = *reinterpret_cast<const uint4*>(&Ytr[tid * 8]);
        *reinterpret_cast<uint4*>(&Ycp[(size_t)tid * CSTR + PADC + tb]) = v;
    }
}

// ---- Kernel C: depthwise temporal conv (92 cols, 4 kernels) + tree cascade.
// 768 threads: lane bits = (g:0-1, i8:2-4, m:5+). Direct global column reads,
// in-register g-butterfly, one barrier.
__global__ __launch_bounds__(768, 6) void conv_tree_k(
    const unsigned short* __restrict__ Ycp,
    const float* __restrict__ Vo,
    const float* __restrict__ Tau,
    const float* __restrict__ Delta,
    const float* __restrict__ W,
    const float* __restrict__ C,
    const float* __restrict__ Theta,
    float* __restrict__ out)
{
    __shared__ __align__(16) float wkp[4 * WSTR];   // 2112 B
    __shared__ float sub[TILE * 25];                // 6400 B
    __shared__ float sTheta[M_DIM];
    __shared__ float sExpC[M_DIM];

    const int tid = threadIdx.x;
    const int t0  = blockIdx.x * TILE;

    // weights: wkp[g*WSTR + c] = wk(g, h=c-13) * W[g], zero outside h in [0,100]
    if (tid < 4 * WSTR) {
        int g = tid / WSTR, c = tid - g * WSTR;
        int h = c - 13;
        float val = 0.f;
        if (h >= 0 && h <= 100) {
            float eD  = __expf(Delta[0]);
            float tt  = fmaxf((float)h - eD, 0.f);
            float tau = __expf(Tau[g]);
            float tf  = tt / tau;
            float fast = tf * __expf(-tf);
            float kv;
            if (g < 2) {
                float ts   = tt / (tau * 2.8f + 10.4f);
                float slow = ts * __expf(-ts) * 0.3f;
                kv = (fast + slow) * (1.0f / 1.3f);
            } else {
                kv = fast;
            }
            val = kv * W[g];
        }
        wkp[tid] = val;
    }
    if (tid < M_DIM) {
        sTheta[tid] = Theta[tid];
        sExpC[tid]  = __expf(C[tid]);
    }
    __syncthreads();

    const int g    = tid & 3;
    const int i8   = (tid >> 2) & 7;
    const int mraw = tid >> 5;                  // 0..23
    const int m    = (mraw < 23) ? mraw : 22;   // clamp spares (write-guarded)
    // column j: j%23 == m, j%4 == g  ->  a = 3*(g-m) mod 4, j = m + 23a
    const int a = (3 * ((g - m) & 3)) & 3;
    const int j = m + 23 * a;
    const unsigned short* colp =
        Ycp + (size_t)j * CSTR + (PADC - 56) + t0 + i8 * 8;

    float acc[8];
    #pragma unroll
    for (int r = 0; r < 8; ++r) acc[r] = 0.f;

    // out[t0+i8*8+r] += Y[t0+i8*8+rb+k-56] * wk[h=rb+k-r-6]; table idx c = rb+k-r+7
    #pragma unroll
    for (int rb = 0; rb < 120; rb += 8) {
        uint4 vv = *reinterpret_cast<const uint4*>(colp + rb);
        float v[8];
        v[0] = bflo(vv.x); v[1] = bfhi(vv.x);
        v[2] = bflo(vv.y); v[3] = bfhi(vv.y);
        v[4] = bflo(vv.z); v[5] = bfhi(vv.z);
        v[6] = bflo(vv.w); v[7] = bfhi(vv.w);
        const float4* wp = reinterpret_cast<const float4*>(&wkp[g * WSTR + rb]);
        float4 w0 = wp[0], w1 = wp[1], w2 = wp[2], w3 = wp[3];
        float wf[16] = { w0.x, w0.y, w0.z, w0.w, w1.x, w1.y, w1.z, w1.w,
                         w2.x, w2.y, w2.z, w2.w, w3.x, w3.y, w3.z, w3.w };
        #pragma unroll
        for (int k = 0; k < 8; ++k) {
            #pragma unroll
            for (int r = 0; r < 8; ++r)
                acc[r] += v[k] * wf[k - r + 7];
        }
    }

    // g-reduction: butterfly over lane bits 0-1
    #pragma unroll
    for (int r = 0; r < 8; ++r) {
        acc[r] += __shfl_xor(acc[r], 1);
        acc[r] += __shfl_xor(acc[r], 2);
    }
    if (g == 0 && mraw < 23) {
        #pragma unroll
        for (int r = 0; r < 8; ++r)
            sub[(i8 * 8 + r) * 25 + m] = acc[r];
    }
    __syncthreads();

    // tree cascade, one thread per timestep
    if (tid < TILE) {
        int t = t0 + tid;
        if (t < T_DIM) {
            const float* s = &sub[tid * 25];
            float o[M_DIM];
            #pragma unroll
            for (int mm = 11; mm < 23; ++mm) {
                float x = s[mm] - sTheta[mm];
                o[mm] = sExpC[mm] / (1.f + __expf(-x));
            }
            #pragma unroll
            for (int r = 10; r >= 0; --r) {
                float x = s[r] + o[2 * r + 1] + o[2 * r + 2] - sTheta[r];
                o[r] = sExpC[r] / (1.f + __expf(-x));
            }
            out[t] = o[0] + Vo[0];
        }
    }
}

extern "C" void kernel_launch(void* const* d_in, const int* in_sizes, int n_in,
                              void* d_out, int out_size, void* d_ws, size_t ws_size,
                              hipStream_t stream) {
    const float* X     = (const float*)d_in[0];
    const float* Vo    = (const float*)d_in[1];
    const float* Tau   = (const float*)d_in[2];
    const float* Delta = (const float*)d_in[3];
    const float* W     = (const float*)d_in[4];
    const float* C     = (const float*)d_in[5];
    const float* Theta = (const float*)d_in[6];
    float* out = (float*)d_out;
    unsigned short* Ycp = (unsigned short*)d_ws;   // 92 * 30208 bf16 = 5.56 MB

    hipMemsetAsync(Ycp, 0, (size_t)92 * CSTR * sizeof(unsigned short), stream);
    reduce_t<<<T_DIM / 8, 256, 0, stream>>>(X, Ycp);
    conv_tree_k<<<(T_DIM + TILE - 1) / TILE, 768, 0, stream>>>(
        Ycp, Vo, Tau, Delta, W, C, Theta, out);
}